// Round 3
// baseline (1225.153 us; speedup 1.0000x reference)
//
#include <hip/hip_runtime.h>
#include <math.h>

#define NPTS 400000
#define K27  27

typedef unsigned short u16;
typedef __bf16 bf16x8 __attribute__((ext_vector_type(8)));
typedef float  f32x4  __attribute__((ext_vector_type(4)));
typedef __attribute__((address_space(1))) void gvoid;
typedef __attribute__((address_space(3))) void lvoid;

__device__ __forceinline__ u16 f2bf(float f) {
    unsigned u = __float_as_uint(f);
    u += 0x7FFFu + ((u >> 16) & 1u);   // RNE round to bf16
    return (u16)(u >> 16);
}
__device__ __forceinline__ unsigned pack2(float lo, float hi) {
    return (unsigned)f2bf(lo) | ((unsigned)f2bf(hi) << 16);
}
__device__ __forceinline__ bf16x8 pack8(float4 x, float4 y) {
    union { uint4 u; bf16x8 v; } r;
    r.u.x = pack2(x.x, x.y); r.u.y = pack2(x.z, x.w);
    r.u.z = pack2(y.x, y.y); r.u.w = pack2(y.z, y.w);
    return r.v;
}
__device__ __forceinline__ bf16x8 zero8() {
    union { uint4 u; bf16x8 v; } r;
    r.u.x = 0; r.u.y = 0; r.u.z = 0; r.u.w = 0;
    return r.v;
}

// ---------------------------------------------------------------------------
// prep: W1 [27][64][38] / W2 [27][38][38] -> [27][48][64] bf16, n-major,
// zero-padded, with the LDS XOR-swizzle PRE-APPLIED to the layout:
//   within each k-chunk, short-offset o = n*64+kc is stored at o ^ ((n&7)<<3).
// global_load_lds then copies linearly; the kernel's ds_read applies the same
// XOR -> conflict-free (2-way) B-fragment reads.
// Also zeroes the padding row (index NPTS) of h and Fb.
// ---------------------------------------------------------------------------
__global__ void prep_w(const float* __restrict__ W1, const float* __restrict__ W2,
                       u16* __restrict__ W1t, u16* __restrict__ W2t,
                       u16* __restrict__ hpad, u16* __restrict__ fpad)
{
    int i = blockIdx.x * 256 + threadIdx.x;
    if (i < 64) {                 // one 64-short row each
        hpad[i] = 0;
        if (fpad) fpad[i] = 0;
    }
    const int TOT = K27 * 48 * 64;
    if (i >= TOT) return;
    int k  = i / (48 * 64);
    int r  = i % (48 * 64);
    int n  = r >> 6;    // 0..47 (out channel)
    int kc = r & 63;    // 0..63 (in channel)
    u16 w1 = 0, w2 = 0;
    if (n < 38) {
        w1 = f2bf(W1[(k * 64 + kc) * 38 + n]);
        if (kc < 38) w2 = f2bf(W2[(k * 38 + kc) * 38 + n]);
    }
    int os = r ^ ((n & 7) << 3);          // pre-swizzled position
    W1t[k * 3072 + os] = w1;
    W2t[k * 3072 + os] = w2;
}

// ---------------------------------------------------------------------------
// prep: features fp32 [N][64] -> bf16 [N][64]  (8 elems / thread)
// ---------------------------------------------------------------------------
__global__ void prep_feat(const float* __restrict__ F, u16* __restrict__ Fb)
{
    size_t i = (size_t)blockIdx.x * 256 + threadIdx.x;
    const size_t TOT = (size_t)NPTS * 64 / 8;              // 3,200,000 exact
    if (i >= TOT) return;
    const float4* fp = (const float4*)(F + i * 8);
    float4 a = fp[0], b = fp[1];
    uint4 v;
    v.x = pack2(a.x, a.y); v.y = pack2(a.z, a.w);
    v.z = pack2(b.x, b.y); v.w = pack2(b.z, b.w);
    *(uint4*)(Fb + i * 8) = v;
}

// ---------------------------------------------------------------------------
// gather-GEMM layer. Pipe-balanced design:
//   A-fragments : direct global gather (TA pipe), reg double-buffered, issued
//                 one k-iteration ahead; indices two ahead.
//   W/B        : global_load_lds staged (pre-swizzled layout), B-fragments
//                 via conflict-free ds_read (DS pipe), double-buffered LDS.
//   vmcnt(12) counted wait before raw s_barrier: only the W-stage retires;
//   the 12 A+idx prefetch loads stay in flight ACROSS the barrier (T4).
// Block = 128 threads (2 waves); wave owns 64 rows (4 row-tiles); grid 3125.
// LAYER==1: -> GELU -> h bf16 [N+1][64] (cols 48..63 zeroed)
// LAYER==2: -> fp32 out [N][38]
// ---------------------------------------------------------------------------
template<int LAYER, bool BF16IN>
__global__ __launch_bounds__(128, 4)
void spconv(const void* __restrict__ in_, const int* __restrict__ nbr,
            const u16* __restrict__ Wt, void* __restrict__ out_)
{
    __shared__ __align__(16) u16 wbuf[2][3072];   // 2 x 6144 B

    const int t    = threadIdx.x;
    const int wave = t >> 6;
    const int lane = t & 63;
    const int quad = lane >> 4;
    const int l16  = lane & 15;

    // bijective XCD-chunk swizzle (nwg=3125, nwg%8!=0 -> m204 variant)
    int bid;
    {
        const int nwg = NPTS / 128, q = nwg / 8, r = nwg % 8;
        int x = blockIdx.x % 8, o = blockIdx.x / 8;
        bid = (x < r ? x * (q + 1) : r * (q + 1) + (x - r) * q) + o;
    }
    const int rbase = bid * 128 + wave * 64;   // 3125*128 == 400000
    const int swz   = (l16 & 7) << 3;          // B-read swizzle (shorts)

    f32x4 acc[4][3] = {};
    bf16x8 aP[4][2], aQ[4][2];
    int iP[4], iQ[4];

    #define GATHER_BF16(dst, ids)                                             \
        {                                                                     \
            const u16* F = (const u16*)in_;                                   \
            _Pragma("unroll")                                                 \
            for (int rt = 0; rt < 4; ++rt) {                                  \
                const u16* rowp = F + (size_t)(ids)[rt] * 64 + quad * 8;      \
                (dst)[rt][0] = *(const bf16x8*)(rowp);                        \
                (dst)[rt][1] = *(const bf16x8*)(rowp + 32);                   \
            }                                                                 \
        }
    #define GATHER_F32(dst, ids)                                              \
        {                                                                     \
            const float* F = (const float*)in_;                               \
            _Pragma("unroll")                                                 \
            for (int rt = 0; rt < 4; ++rt) {                                  \
                if ((ids)[rt] < NPTS) {                                       \
                    const float* rowp = F + (size_t)(ids)[rt] * 64 + quad * 8;\
                    float4 f0 = *(const float4*)(rowp);                       \
                    float4 f1 = *(const float4*)(rowp + 4);                   \
                    float4 f2 = *(const float4*)(rowp + 32);                  \
                    float4 f3 = *(const float4*)(rowp + 36);                  \
                    (dst)[rt][0] = pack8(f0, f1);                             \
                    (dst)[rt][1] = pack8(f2, f3);                             \
                } else {                                                      \
                    (dst)[rt][0] = zero8();                                   \
                    (dst)[rt][1] = zero8();                                   \
                }                                                             \
            }                                                                 \
        }
    #define GATHER(dst, ids) { if (BF16IN) GATHER_BF16(dst, ids) else GATHER_F32(dst, ids) }

    #define STAGE_W(KW, BSEL)                                                 \
        {                                                                     \
            const u16* g_ = Wt + (size_t)(KW) * 3072 + t * 8;                 \
            u16* l_ = &wbuf[(BSEL)][t * 8];                                   \
            _Pragma("unroll")                                                 \
            for (int r3 = 0; r3 < 3; ++r3)                                    \
                __builtin_amdgcn_global_load_lds((gvoid*)(g_ + r3 * 1024),    \
                                                 (lvoid*)(l_ + r3 * 1024),    \
                                                 16, 0, 0);                   \
        }

    // ---------------- prologue ----------------
    #pragma unroll
    for (int rt = 0; rt < 4; ++rt) iP[rt] = nbr[rbase + rt * 16 + l16];
    GATHER(aP, iP);                                   // A_0 (auto vmcnt wait)
    #pragma unroll
    for (int rt = 0; rt < 4; ++rt) iQ[rt] = nbr[(size_t)NPTS + rbase + rt * 16 + l16];
    STAGE_W(0, 0);
    STAGE_W(1, 1);
    __builtin_amdgcn_sched_barrier(0);
    asm volatile("s_waitcnt vmcnt(3)");               // A0,idx1,W0 done; W1 in flight
    __builtin_amdgcn_s_barrier();
    __builtin_amdgcn_sched_barrier(0);

    // ---------------- main loop ----------------
    // ITER(k): consume ACUR(A_k)/B_k, issue INXT(idx_{k+2}) + ANXT(A_{k+1}),
    // counted-vmcnt barrier, stage W[k+2] into buf[k&1].
    #define ITER(KK, ACUR, ANXT, ICUR, INXT)                                  \
      {                                                                       \
        const int k_ = (KK);                                                  \
        /* region 1: B ds_read + idx_{k+2} + A_{k+1} issue */                 \
        bf16x8 bfr[3][2];                                                     \
        {                                                                     \
            const u16* wb = &wbuf[k_ & 1][0];                                 \
            _Pragma("unroll")                                                 \
            for (int nt = 0; nt < 3; ++nt)                                    \
                _Pragma("unroll")                                             \
                for (int ks = 0; ks < 2; ++ks)                                \
                    bfr[nt][ks] = *(const bf16x8*)&wb[(nt * 16 + l16) * 64    \
                                        + ((ks * 32 + quad * 8) ^ swz)];      \
        }                                                                     \
        {                                                                     \
            int kf = k_ + 2; if (kf > K27 - 1) kf = K27 - 1;                  \
            const int* nr = nbr + (size_t)kf * NPTS + rbase;                  \
            _Pragma("unroll")                                                 \
            for (int rt = 0; rt < 4; ++rt) INXT[rt] = nr[rt * 16 + l16];      \
        }                                                                     \
        GATHER(ANXT, ICUR);                                                   \
        __builtin_amdgcn_sched_barrier(0);                                    \
        /* region 2: MFMA on resident A_k / B_k */                            \
        _Pragma("unroll")                                                     \
        for (int ks = 0; ks < 2; ++ks)                                        \
            _Pragma("unroll")                                                 \
            for (int rt = 0; rt < 4; ++rt)                                    \
                _Pragma("unroll")                                             \
                for (int nt = 0; nt < 3; ++nt)                                \
                    acc[rt][nt] = __builtin_amdgcn_mfma_f32_16x16x32_bf16(    \
                        ACUR[rt][ks], bfr[nt][ks], acc[rt][nt], 0, 0, 0);     \
        __builtin_amdgcn_sched_barrier(0);                                    \
        /* region 3: retire ONLY the W[k+1] stage, barrier */                 \
        if (BF16IN) { asm volatile("s_waitcnt vmcnt(12)"); }                  \
        else        { asm volatile("s_waitcnt vmcnt(20)"); }                  \
        __builtin_amdgcn_s_barrier();                                         \
        __builtin_amdgcn_sched_barrier(0);                                    \
        /* region 4: stage W[k+2] into buf[k&1] (now free) */                 \
        {                                                                     \
            int kw = k_ + 2; if (kw > K27 - 1) kw = K27 - 1;                  \
            STAGE_W(kw, k_ & 1);                                              \
        }                                                                     \
        __builtin_amdgcn_sched_barrier(0);                                    \
      }

    for (int k = 0; k < K27 - 1; k += 2) {   // 13 pairs: k = 0..25
        ITER(k,     aP, aQ, iQ, iP);
        ITER(k + 1, aQ, aP, iP, iQ);
    }
    ITER(K27 - 1, aP, aQ, iQ, iP);           // k = 26

    // ---------------- epilogue (C layout: col = l16, row = quad*4 + r) ----
    if (LAYER == 1) {
        u16* h = (u16*)out_;
        #pragma unroll
        for (int rt = 0; rt < 4; ++rt) {
            #pragma unroll
            for (int r = 0; r < 4; ++r) {
                size_t ro = (size_t)(rbase + rt * 16 + quad * 4 + r) * 64;
                #pragma unroll
                for (int nt = 0; nt < 3; ++nt) {
                    float x = acc[rt][nt][r];
                    float g = 0.5f * x * (1.0f + erff(x * 0.70710678118654752f));
                    h[ro + nt * 16 + l16] = f2bf(g);
                }
                h[ro + 48 + l16] = 0;      // zero pad cols 48..63
            }
        }
    } else {
        float* out = (float*)out_;
        #pragma unroll
        for (int rt = 0; rt < 4; ++rt) {
            #pragma unroll
            for (int nt = 0; nt < 3; ++nt) {
                int col = nt * 16 + l16;
                if (col < 38) {
                    #pragma unroll
                    for (int r = 0; r < 4; ++r) {
                        int row = rbase + rt * 16 + quad * 4 + r;
                        out[(size_t)row * 38 + col] = acc[rt][nt][r];
                    }
                }
            }
        }
    }
    #undef ITER
    #undef STAGE_W
    #undef GATHER
    #undef GATHER_BF16
    #undef GATHER_F32
}

// ---------------------------------------------------------------------------
extern "C" void kernel_launch(void* const* d_in, const int* in_sizes, int n_in,
                              void* d_out, int out_size, void* d_ws, size_t ws_size,
                              hipStream_t stream)
{
    const float* feat = (const float*)d_in[0];   // [N][64] fp32
    const int*   nbr  = (const int*)  d_in[1];   // [27][N] int32, N == pad idx
    const float* W1   = (const float*)d_in[2];   // [27][64][38]
    const float* W2   = (const float*)d_in[3];   // [27][38][38]

    const size_t hbytes = (size_t)(NPTS + 1) * 64 * 2;   // h incl. zero pad row
    const size_t wbytes = (size_t)K27 * 48 * 64 * 2;     // 165,888

    char* ws  = (char*)d_ws;
    u16* h    = (u16*)ws;
    u16* W1t  = (u16*)(ws + hbytes);
    u16* W2t  = (u16*)(ws + hbytes + wbytes);
    u16* Fb   = (u16*)(ws + hbytes + 2 * wbytes);
    const bool full = ws_size >= hbytes * 2 + 2 * wbytes;   // bf16 feature copy fits?

    prep_w<<<(K27 * 48 * 64 + 255) / 256, 256, 0, stream>>>(
        W1, W2, W1t, W2t,
        h + (size_t)NPTS * 64,
        full ? Fb + (size_t)NPTS * 64 : (u16*)nullptr);

    const int nblk = NPTS / 128;   // 3125, exact
    if (full) {
        prep_feat<<<(int)(((size_t)NPTS * 64 / 8 + 255) / 256), 256, 0, stream>>>(feat, Fb);
        spconv<1, true ><<<nblk, 128, 0, stream>>>(Fb,   nbr, W1t, h);
    } else {
        spconv<1, false><<<nblk, 128, 0, stream>>>(feat, nbr, W1t, h);
    }
    spconv<2, true ><<<nblk, 128, 0, stream>>>(h, nbr, W2t, d_out);
}

// Round 4
// 417.756 us; speedup vs baseline: 2.9327x; 2.9327x over previous
//
#include <hip/hip_runtime.h>
#include <math.h>

#define NPTS 400000
#define K27  27

typedef unsigned short u16;
typedef __bf16 bf16x8 __attribute__((ext_vector_type(8)));
typedef float  f32x4  __attribute__((ext_vector_type(4)));
typedef __attribute__((address_space(1))) void gvoid;
typedef __attribute__((address_space(3))) void lvoid;

__device__ __forceinline__ u16 f2bf(float f) {
    unsigned u = __float_as_uint(f);
    u += 0x7FFFu + ((u >> 16) & 1u);   // RNE round to bf16
    return (u16)(u >> 16);
}
__device__ __forceinline__ unsigned pack2(float lo, float hi) {
    return (unsigned)f2bf(lo) | ((unsigned)f2bf(hi) << 16);
}
__device__ __forceinline__ bf16x8 pack8(float4 x, float4 y) {
    union { uint4 u; bf16x8 v; } r;
    r.u.x = pack2(x.x, x.y); r.u.y = pack2(x.z, x.w);
    r.u.z = pack2(y.x, y.y); r.u.w = pack2(y.z, y.w);
    return r.v;
}
__device__ __forceinline__ bf16x8 zero8() {
    union { uint4 u; bf16x8 v; } r;
    r.u.x = 0; r.u.y = 0; r.u.z = 0; r.u.w = 0;
    return r.v;
}

// ---------------------------------------------------------------------------
// prep: W1 [27][64][38] / W2 [27][38][38] -> [27][48][64] bf16, n-major,
// zero-padded, with the LDS XOR-swizzle PRE-APPLIED to the layout:
//   within each k-chunk, short-offset o = n*64+kc is stored at o ^ ((n&7)<<3).
// global_load_lds copies linearly; the kernel's ds_read applies the same XOR.
// Also zeroes the padding row (index NPTS) of h and Fb.
// ---------------------------------------------------------------------------
__global__ void prep_w(const float* __restrict__ W1, const float* __restrict__ W2,
                       u16* __restrict__ W1t, u16* __restrict__ W2t,
                       u16* __restrict__ hpad, u16* __restrict__ fpad)
{
    int i = blockIdx.x * 256 + threadIdx.x;
    if (i < 64) {                 // one 64-short row each
        hpad[i] = 0;
        if (fpad) fpad[i] = 0;
    }
    const int TOT = K27 * 48 * 64;
    if (i >= TOT) return;
    int k  = i / (48 * 64);
    int r  = i % (48 * 64);
    int n  = r >> 6;    // 0..47 (out channel)
    int kc = r & 63;    // 0..63 (in channel)
    u16 w1 = 0, w2 = 0;
    if (n < 38) {
        w1 = f2bf(W1[(k * 64 + kc) * 38 + n]);
        if (kc < 38) w2 = f2bf(W2[(k * 38 + kc) * 38 + n]);
    }
    int os = r ^ ((n & 7) << 3);          // pre-swizzled position
    W1t[k * 3072 + os] = w1;
    W2t[k * 3072 + os] = w2;
}

// ---------------------------------------------------------------------------
// prep: features fp32 [N][64] -> bf16 [N][64]  (8 elems / thread)
// ---------------------------------------------------------------------------
__global__ void prep_feat(const float* __restrict__ F, u16* __restrict__ Fb)
{
    size_t i = (size_t)blockIdx.x * 256 + threadIdx.x;
    const size_t TOT = (size_t)NPTS * 64 / 8;              // 3,200,000 exact
    if (i >= TOT) return;
    const float4* fp = (const float4*)(F + i * 8);
    float4 a = fp[0], b = fp[1];
    uint4 v;
    v.x = pack2(a.x, a.y); v.y = pack2(a.z, a.w);
    v.z = pack2(b.x, b.y); v.w = pack2(b.z, b.w);
    *(uint4*)(Fb + i * 8) = v;
}

// ---------------------------------------------------------------------------
// gather-GEMM layer. Pipe-balanced, REGISTER-BUDGETED (round-3 spilled):
//   A-fragments : direct global gather, reg ping/pong (2 row-tiles -> 32 regs)
//   W/B         : global_load_lds double-buffered LDS, swizzled ds_read
//   counted vmcnt(6) before raw s_barrier: prev W-stage retires, the 6 A/idx
//   prefetch loads stay in flight across the barrier.
// Block = 128 threads (2 waves); wave owns 32 rows (2 row-tiles); grid 6250.
// __launch_bounds__(128,3): VGPR cap ~168 -> no spill, 3 waves/SIMD.
// LAYER==1: -> GELU -> h bf16 [N+1][64] (cols 48..63 zeroed)
// LAYER==2: -> fp32 out [N][38]
// ---------------------------------------------------------------------------
template<int LAYER, bool BF16IN>
__global__ __launch_bounds__(128, 3)
void spconv(const void* __restrict__ in_, const int* __restrict__ nbr,
            const u16* __restrict__ Wt, void* __restrict__ out_)
{
    __shared__ __align__(16) u16 wbuf[2][3072];   // 2 x 6144 B

    const int t    = threadIdx.x;
    const int wave = t >> 6;
    const int lane = t & 63;
    const int quad = lane >> 4;
    const int l16  = lane & 15;

    // bijective XCD-chunk swizzle (nwg=6250, nwg%8 = 2 -> m204 variant)
    int bid;
    {
        const int nwg = NPTS / 64, q = nwg / 8, r = nwg % 8;
        int x = blockIdx.x % 8, o = blockIdx.x / 8;
        bid = (x < r ? x * (q + 1) : r * (q + 1) + (x - r) * q) + o;
    }
    const int rbase = bid * 64 + wave * 32;    // 6250*64 == 400000
    const int swz   = (l16 & 7) << 3;          // B-read swizzle (shorts)

    f32x4 acc[2][3] = {};
    bf16x8 aP[2][2], aQ[2][2];
    int iP[2], iQ[2];

    #define GATHER_BF16(dst, ids)                                             \
        {                                                                     \
            const u16* F = (const u16*)in_;                                   \
            _Pragma("unroll")                                                 \
            for (int rt = 0; rt < 2; ++rt) {                                  \
                const u16* rowp = F + (size_t)(ids)[rt] * 64 + quad * 8;      \
                (dst)[rt][0] = *(const bf16x8*)(rowp);                        \
                (dst)[rt][1] = *(const bf16x8*)(rowp + 32);                   \
            }                                                                 \
        }
    #define GATHER_F32(dst, ids)                                              \
        {                                                                     \
            const float* F = (const float*)in_;                               \
            _Pragma("unroll")                                                 \
            for (int rt = 0; rt < 2; ++rt) {                                  \
                if ((ids)[rt] < NPTS) {                                       \
                    const float* rowp = F + (size_t)(ids)[rt] * 64 + quad * 8;\
                    float4 f0 = *(const float4*)(rowp);                       \
                    float4 f1 = *(const float4*)(rowp + 4);                   \
                    float4 f2 = *(const float4*)(rowp + 32);                  \
                    float4 f3 = *(const float4*)(rowp + 36);                  \
                    (dst)[rt][0] = pack8(f0, f1);                             \
                    (dst)[rt][1] = pack8(f2, f3);                             \
                } else {                                                      \
                    (dst)[rt][0] = zero8();                                   \
                    (dst)[rt][1] = zero8();                                   \
                }                                                             \
            }                                                                 \
        }
    #define GATHER(dst, ids) { if (BF16IN) GATHER_BF16(dst, ids) else GATHER_F32(dst, ids) }

    #define STAGE_W(KW, BSEL)                                                 \
        {                                                                     \
            const u16* g_ = Wt + (size_t)(KW) * 3072 + t * 8;                 \
            u16* l_ = &wbuf[(BSEL)][t * 8];                                   \
            _Pragma("unroll")                                                 \
            for (int r3 = 0; r3 < 3; ++r3)                                    \
                __builtin_amdgcn_global_load_lds((gvoid*)(g_ + r3 * 1024),    \
                                                 (lvoid*)(l_ + r3 * 1024),    \
                                                 16, 0, 0);                   \
        }

    // ---------------- prologue ----------------
    #pragma unroll
    for (int rt = 0; rt < 2; ++rt) iP[rt] = nbr[rbase + rt * 16 + l16];
    GATHER(aP, iP);                                   // A_0
    #pragma unroll
    for (int rt = 0; rt < 2; ++rt) iQ[rt] = nbr[(size_t)NPTS + rbase + rt * 16 + l16];
    STAGE_W(0, 0);
    STAGE_W(1, 1);
    __builtin_amdgcn_sched_barrier(0);
    asm volatile("s_waitcnt vmcnt(3)");               // A0,idx1,W0 done; W1 in flight
    __builtin_amdgcn_s_barrier();
    __builtin_amdgcn_sched_barrier(0);

    // ---------------- main loop ----------------
    // ITER(k): consume ACUR(A_k)/B_k, issue INXT(idx_{k+2}) + ANXT(A_{k+1}),
    // counted-vmcnt barrier (prev W retires, A/idx stay in flight),
    // stage W[k+2] into buf[k&1].
    #define ITER(KK, ACUR, ANXT, ICUR, INXT)                                  \
      {                                                                       \
        const int k_ = (KK);                                                  \
        /* region 1: B ds_read + idx_{k+2} + A_{k+1} issue */                 \
        bf16x8 bfr[3][2];                                                     \
        {                                                                     \
            const u16* wb = &wbuf[k_ & 1][0];                                 \
            _Pragma("unroll")                                                 \
            for (int nt = 0; nt < 3; ++nt)                                    \
                _Pragma("unroll")                                             \
                for (int ks = 0; ks < 2; ++ks)                                \
                    bfr[nt][ks] = *(const bf16x8*)&wb[(nt * 16 + l16) * 64    \
                                        + ((ks * 32 + quad * 8) ^ swz)];      \
        }                                                                     \
        {                                                                     \
            int kf = k_ + 2; if (kf > K27 - 1) kf = K27 - 1;                  \
            const int* nr = nbr + (size_t)kf * NPTS + rbase;                  \
            _Pragma("unroll")                                                 \
            for (int rt = 0; rt < 2; ++rt) INXT[rt] = nr[rt * 16 + l16];      \
        }                                                                     \
        GATHER(ANXT, ICUR);                                                   \
        __builtin_amdgcn_sched_barrier(0);                                    \
        /* region 2: MFMA on resident A_k / B_k */                            \
        _Pragma("unroll")                                                     \
        for (int ks = 0; ks < 2; ++ks)                                        \
            _Pragma("unroll")                                                 \
            for (int rt = 0; rt < 2; ++rt)                                    \
                _Pragma("unroll")                                             \
                for (int nt = 0; nt < 3; ++nt)                                \
                    acc[rt][nt] = __builtin_amdgcn_mfma_f32_16x16x32_bf16(    \
                        ACUR[rt][ks], bfr[nt][ks], acc[rt][nt], 0, 0, 0);     \
        __builtin_amdgcn_sched_barrier(0);                                    \
        /* region 3: retire ONLY the prev W stage, barrier */                 \
        if (BF16IN) { asm volatile("s_waitcnt vmcnt(6)"); }                   \
        else        { asm volatile("s_waitcnt vmcnt(10)"); }                  \
        __builtin_amdgcn_s_barrier();                                         \
        __builtin_amdgcn_sched_barrier(0);                                    \
        /* region 4: stage W[k+2] into buf[k&1] (now free) */                 \
        {                                                                     \
            int kw = k_ + 2; if (kw > K27 - 1) kw = K27 - 1;                  \
            STAGE_W(kw, k_ & 1);                                              \
        }                                                                     \
        __builtin_amdgcn_sched_barrier(0);                                    \
      }

    for (int k = 0; k < K27 - 1; k += 2) {   // 13 pairs: k = 0..25
        ITER(k,     aP, aQ, iQ, iP);
        ITER(k + 1, aQ, aP, iP, iQ);
    }
    ITER(K27 - 1, aP, aQ, iQ, iP);           // k = 26

    // ---------------- epilogue (C layout: col = l16, row = quad*4 + r) ----
    if (LAYER == 1) {
        u16* h = (u16*)out_;
        #pragma unroll
        for (int rt = 0; rt < 2; ++rt) {
            #pragma unroll
            for (int r = 0; r < 4; ++r) {
                size_t ro = (size_t)(rbase + rt * 16 + quad * 4 + r) * 64;
                #pragma unroll
                for (int nt = 0; nt < 3; ++nt) {
                    float x = acc[rt][nt][r];
                    float g = 0.5f * x * (1.0f + erff(x * 0.70710678118654752f));
                    h[ro + nt * 16 + l16] = f2bf(g);
                }
                h[ro + 48 + l16] = 0;      // zero pad cols 48..63
            }
        }
    } else {
        float* out = (float*)out_;
        #pragma unroll
        for (int rt = 0; rt < 2; ++rt) {
            #pragma unroll
            for (int nt = 0; nt < 3; ++nt) {
                int col = nt * 16 + l16;
                if (col < 38) {
                    #pragma unroll
                    for (int r = 0; r < 4; ++r) {
                        int row = rbase + rt * 16 + quad * 4 + r;
                        out[(size_t)row * 38 + col] = acc[rt][nt][r];
                    }
                }
            }
        }
    }
    #undef ITER
    #undef STAGE_W
    #undef GATHER
    #undef GATHER_BF16
    #undef GATHER_F32
}

// ---------------------------------------------------------------------------
extern "C" void kernel_launch(void* const* d_in, const int* in_sizes, int n_in,
                              void* d_out, int out_size, void* d_ws, size_t ws_size,
                              hipStream_t stream)
{
    const float* feat = (const float*)d_in[0];   // [N][64] fp32
    const int*   nbr  = (const int*)  d_in[1];   // [27][N] int32, N == pad idx
    const float* W1   = (const float*)d_in[2];   // [27][64][38]
    const float* W2   = (const float*)d_in[3];   // [27][38][38]

    const size_t hbytes = (size_t)(NPTS + 1) * 64 * 2;   // h incl. zero pad row
    const size_t wbytes = (size_t)K27 * 48 * 64 * 2;     // 165,888

    char* ws  = (char*)d_ws;
    u16* h    = (u16*)ws;
    u16* W1t  = (u16*)(ws + hbytes);
    u16* W2t  = (u16*)(ws + hbytes + wbytes);
    u16* Fb   = (u16*)(ws + hbytes + 2 * wbytes);
    const bool full = ws_size >= hbytes * 2 + 2 * wbytes;   // bf16 feature copy fits?

    prep_w<<<(K27 * 48 * 64 + 255) / 256, 256, 0, stream>>>(
        W1, W2, W1t, W2t,
        h + (size_t)NPTS * 64,
        full ? Fb + (size_t)NPTS * 64 : (u16*)nullptr);

    const int nblk = NPTS / 64;   // 6250, exact
    if (full) {
        prep_feat<<<(int)(((size_t)NPTS * 64 / 8 + 255) / 256), 256, 0, stream>>>(feat, Fb);
        spconv<1, true ><<<nblk, 128, 0, stream>>>(Fb,   nbr, W1t, h);
    } else {
        spconv<1, false><<<nblk, 128, 0, stream>>>(feat, nbr, W1t, h);
    }
    spconv<2, true ><<<nblk, 128, 0, stream>>>(h, nbr, W2t, d_out);
}

// Round 5
// 411.992 us; speedup vs baseline: 2.9737x; 1.0140x over previous
//
#include <hip/hip_runtime.h>
#include <math.h>

#define NPTS 400000
#define K27  27
#define WSTRIDE 4096   // shorts per k-tile in Wt (48*64=3072 used + pad -> 8KB)

typedef unsigned short u16;
typedef __bf16 bf16x8 __attribute__((ext_vector_type(8)));
typedef float  f32x4  __attribute__((ext_vector_type(4)));
typedef __attribute__((address_space(1))) void gvoid;
typedef __attribute__((address_space(3))) void lvoid;

__device__ __forceinline__ u16 f2bf(float f) {
    unsigned u = __float_as_uint(f);
    u += 0x7FFFu + ((u >> 16) & 1u);   // RNE round to bf16
    return (u16)(u >> 16);
}
__device__ __forceinline__ unsigned pack2(float lo, float hi) {
    return (unsigned)f2bf(lo) | ((unsigned)f2bf(hi) << 16);
}
__device__ __forceinline__ bf16x8 pack8(float4 x, float4 y) {
    union { uint4 u; bf16x8 v; } r;
    r.u.x = pack2(x.x, x.y); r.u.y = pack2(x.z, x.w);
    r.u.z = pack2(y.x, y.y); r.u.w = pack2(y.z, y.w);
    return r.v;
}
__device__ __forceinline__ bf16x8 zero8() {
    union { uint4 u; bf16x8 v; } r;
    r.u.x = 0; r.u.y = 0; r.u.z = 0; r.u.w = 0;
    return r.v;
}

// ---------------------------------------------------------------------------
// prep: W1 [27][64][38] / W2 [27][38][38] -> [27][WSTRIDE] bf16 tiles
// (48x64 n-major, zero-padded) with the LDS XOR-swizzle PRE-APPLIED:
//   short-offset o = n*64+kc stored at o ^ ((n&7)<<3).
// global_load_lds copies linearly; the kernel's ds_read applies the same XOR.
// Also zeroes the padding row (index NPTS) of h and Fb.
// ---------------------------------------------------------------------------
__global__ void prep_w(const float* __restrict__ W1, const float* __restrict__ W2,
                       u16* __restrict__ W1t, u16* __restrict__ W2t,
                       u16* __restrict__ hpad, u16* __restrict__ fpad)
{
    int i = blockIdx.x * 256 + threadIdx.x;
    if (i < 64) {                 // one 64-short row each
        hpad[i] = 0;
        if (fpad) fpad[i] = 0;
    }
    const int TOT = K27 * 48 * 64;
    if (i >= TOT) return;
    int k  = i / (48 * 64);
    int r  = i % (48 * 64);
    int n  = r >> 6;    // 0..47 (out channel)
    int kc = r & 63;    // 0..63 (in channel)
    u16 w1 = 0, w2 = 0;
    if (n < 38) {
        w1 = f2bf(W1[(k * 64 + kc) * 38 + n]);
        if (kc < 38) w2 = f2bf(W2[(k * 38 + kc) * 38 + n]);
    }
    int os = r ^ ((n & 7) << 3);          // pre-swizzled position
    W1t[k * WSTRIDE + os] = w1;
    W2t[k * WSTRIDE + os] = w2;
}

// ---------------------------------------------------------------------------
// prep: features fp32 [N][64] -> bf16 [N][64]  (8 elems / thread)
// ---------------------------------------------------------------------------
__global__ void prep_feat(const float* __restrict__ F, u16* __restrict__ Fb)
{
    size_t i = (size_t)blockIdx.x * 256 + threadIdx.x;
    const size_t TOT = (size_t)NPTS * 64 / 8;              // 3,200,000 exact
    if (i >= TOT) return;
    const float4* fp = (const float4*)(F + i * 8);
    float4 a = fp[0], b = fp[1];
    uint4 v;
    v.x = pack2(a.x, a.y); v.y = pack2(a.z, a.w);
    v.z = pack2(b.x, b.y); v.w = pack2(b.z, b.w);
    *(uint4*)(Fb + i * 8) = v;
}

// ---------------------------------------------------------------------------
// gather-GEMM layer. Round-5: 4-wave blocks for LDS amortization + residency.
//   A-fragments : direct global gather, reg ping/pong (2 row-tiles/wave)
//   W/B         : global_load_lds double-buffered LDS (8KB tiles, 2 uniform
//                 instr/thread), swizzled conflict-free ds_read
//   counted vmcnt(6) before raw s_barrier: prev W-stage retires, the 6 A/idx
//   prefetch loads stay in flight across the barrier.
// Block = 256 threads (4 waves) x 32 rows/wave = 128 rows; grid 3125 exact.
// LAYER==1: -> GELU -> h bf16 [N+1][64] (cols 48..63 zeroed)
// LAYER==2: -> fp32 out [N][38]
// ---------------------------------------------------------------------------
template<int LAYER, bool BF16IN>
__global__ __launch_bounds__(256, 4)
void spconv(const void* __restrict__ in_, const int* __restrict__ nbr,
            const u16* __restrict__ Wt, void* __restrict__ out_)
{
    __shared__ __align__(16) u16 wbuf[2][WSTRIDE];   // 2 x 8192 B

    const int t    = threadIdx.x;
    const int wave = t >> 6;
    const int lane = t & 63;
    const int quad = lane >> 4;
    const int l16  = lane & 15;

    // bijective XCD-chunk swizzle (nwg=3125, nwg%8=5 -> m204 variant)
    int bid;
    {
        const int nwg = NPTS / 128, q = nwg / 8, r = nwg % 8;
        int x = blockIdx.x % 8, o = blockIdx.x / 8;
        bid = (x < r ? x * (q + 1) : r * (q + 1) + (x - r) * q) + o;
    }
    const int rbase = bid * 128 + wave * 32;   // 3125*128 == 400000
    const int swz   = (l16 & 7) << 3;          // B-read swizzle (shorts)

    f32x4 acc[2][3] = {};
    bf16x8 aP[2][2], aQ[2][2];
    int iP[2], iQ[2];

    #define GATHER_BF16(dst, ids)                                             \
        {                                                                     \
            const u16* F = (const u16*)in_;                                   \
            _Pragma("unroll")                                                 \
            for (int rt = 0; rt < 2; ++rt) {                                  \
                const u16* rowp = F + (size_t)(ids)[rt] * 64 + quad * 8;      \
                (dst)[rt][0] = *(const bf16x8*)(rowp);                        \
                (dst)[rt][1] = *(const bf16x8*)(rowp + 32);                   \
            }                                                                 \
        }
    #define GATHER_F32(dst, ids)                                              \
        {                                                                     \
            const float* F = (const float*)in_;                               \
            _Pragma("unroll")                                                 \
            for (int rt = 0; rt < 2; ++rt) {                                  \
                if ((ids)[rt] < NPTS) {                                       \
                    const float* rowp = F + (size_t)(ids)[rt] * 64 + quad * 8;\
                    float4 f0 = *(const float4*)(rowp);                       \
                    float4 f1 = *(const float4*)(rowp + 4);                   \
                    float4 f2 = *(const float4*)(rowp + 32);                  \
                    float4 f3 = *(const float4*)(rowp + 36);                  \
                    (dst)[rt][0] = pack8(f0, f1);                             \
                    (dst)[rt][1] = pack8(f2, f3);                             \
                } else {                                                      \
                    (dst)[rt][0] = zero8();                                   \
                    (dst)[rt][1] = zero8();                                   \
                }                                                             \
            }                                                                 \
        }
    #define GATHER(dst, ids) { if (BF16IN) GATHER_BF16(dst, ids) else GATHER_F32(dst, ids) }

    // 8KB tile, 256 threads x 2 chunks of 16B; per-wave base + lane*16 layout
    #define STAGE_W(KW, BSEL)                                                 \
        {                                                                     \
            const u16* g_ = Wt + (size_t)(KW) * WSTRIDE + t * 8;              \
            u16* l_ = &wbuf[(BSEL)][t * 8];                                   \
            __builtin_amdgcn_global_load_lds((gvoid*)(g_),                    \
                                             (lvoid*)(l_), 16, 0, 0);         \
            __builtin_amdgcn_global_load_lds((gvoid*)(g_ + 2048),             \
                                             (lvoid*)(l_ + 2048), 16, 0, 0);  \
        }

    // ---------------- prologue ----------------
    #pragma unroll
    for (int rt = 0; rt < 2; ++rt) iP[rt] = nbr[rbase + rt * 16 + l16];
    GATHER(aP, iP);                                   // A_0
    #pragma unroll
    for (int rt = 0; rt < 2; ++rt) iQ[rt] = nbr[(size_t)NPTS + rbase + rt * 16 + l16];
    STAGE_W(0, 0);
    STAGE_W(1, 1);
    __builtin_amdgcn_sched_barrier(0);
    asm volatile("s_waitcnt vmcnt(2)");               // retire through W0; W1 in flight
    __builtin_amdgcn_s_barrier();
    __builtin_amdgcn_sched_barrier(0);

    // ---------------- main loop ----------------
    // ITER(k): consume ACUR(A_k)/B_k, issue INXT(idx_{k+2}) + ANXT(A_{k+1}),
    // counted-vmcnt barrier (prev W retires, A/idx stay in flight),
    // stage W[k+2] into buf[k&1].
    #define ITER(KK, ACUR, ANXT, ICUR, INXT)                                  \
      {                                                                       \
        const int k_ = (KK);                                                  \
        /* region 1: B ds_read + idx_{k+2} + A_{k+1} issue */                 \
        bf16x8 bfr[3][2];                                                     \
        {                                                                     \
            const u16* wb = &wbuf[k_ & 1][0];                                 \
            _Pragma("unroll")                                                 \
            for (int nt = 0; nt < 3; ++nt)                                    \
                _Pragma("unroll")                                             \
                for (int ks = 0; ks < 2; ++ks)                                \
                    bfr[nt][ks] = *(const bf16x8*)&wb[(nt * 16 + l16) * 64    \
                                        + ((ks * 32 + quad * 8) ^ swz)];      \
        }                                                                     \
        {                                                                     \
            int kf = k_ + 2; if (kf > K27 - 1) kf = K27 - 1;                  \
            const int* nr = nbr + (size_t)kf * NPTS + rbase;                  \
            _Pragma("unroll")                                                 \
            for (int rt = 0; rt < 2; ++rt) INXT[rt] = nr[rt * 16 + l16];      \
        }                                                                     \
        GATHER(ANXT, ICUR);                                                   \
        __builtin_amdgcn_sched_barrier(0);                                    \
        /* region 2: MFMA on resident A_k / B_k */                            \
        _Pragma("unroll")                                                     \
        for (int ks = 0; ks < 2; ++ks)                                        \
            _Pragma("unroll")                                                 \
            for (int rt = 0; rt < 2; ++rt)                                    \
                _Pragma("unroll")                                             \
                for (int nt = 0; nt < 3; ++nt)                                \
                    acc[rt][nt] = __builtin_amdgcn_mfma_f32_16x16x32_bf16(    \
                        ACUR[rt][ks], bfr[nt][ks], acc[rt][nt], 0, 0, 0);     \
        __builtin_amdgcn_sched_barrier(0);                                    \
        /* region 3: retire ONLY the prev W stage, barrier */                 \
        if (BF16IN) { asm volatile("s_waitcnt vmcnt(6)"); }                   \
        else        { asm volatile("s_waitcnt vmcnt(10)"); }                  \
        __builtin_amdgcn_s_barrier();                                         \
        __builtin_amdgcn_sched_barrier(0);                                    \
        /* region 4: stage W[k+2] into buf[k&1] (now free) */                 \
        {                                                                     \
            int kw = k_ + 2; if (kw > K27 - 1) kw = K27 - 1;                  \
            STAGE_W(kw, k_ & 1);                                              \
        }                                                                     \
        __builtin_amdgcn_sched_barrier(0);                                    \
      }

    for (int k = 0; k < K27 - 1; k += 2) {   // 13 pairs: k = 0..25
        ITER(k,     aP, aQ, iQ, iP);
        ITER(k + 1, aQ, aP, iP, iQ);
    }
    ITER(K27 - 1, aP, aQ, iQ, iP);           // k = 26

    // ---------------- epilogue (C layout: col = l16, row = quad*4 + r) ----
    if (LAYER == 1) {
        u16* h = (u16*)out_;
        #pragma unroll
        for (int rt = 0; rt < 2; ++rt) {
            #pragma unroll
            for (int r = 0; r < 4; ++r) {
                size_t ro = (size_t)(rbase + rt * 16 + quad * 4 + r) * 64;
                #pragma unroll
                for (int nt = 0; nt < 3; ++nt) {
                    float x = acc[rt][nt][r];
                    float g = 0.5f * x * (1.0f + erff(x * 0.70710678118654752f));
                    h[ro + nt * 16 + l16] = f2bf(g);
                }
                h[ro + 48 + l16] = 0;      // zero pad cols 48..63
            }
        }
    } else {
        float* out = (float*)out_;
        #pragma unroll
        for (int rt = 0; rt < 2; ++rt) {
            #pragma unroll
            for (int nt = 0; nt < 3; ++nt) {
                int col = nt * 16 + l16;
                if (col < 38) {
                    #pragma unroll
                    for (int r = 0; r < 4; ++r) {
                        int row = rbase + rt * 16 + quad * 4 + r;
                        out[(size_t)row * 38 + col] = acc[rt][nt][r];
                    }
                }
            }
        }
    }
    #undef ITER
    #undef STAGE_W
    #undef GATHER
    #undef GATHER_BF16
    #undef GATHER_F32
}

// ---------------------------------------------------------------------------
extern "C" void kernel_launch(void* const* d_in, const int* in_sizes, int n_in,
                              void* d_out, int out_size, void* d_ws, size_t ws_size,
                              hipStream_t stream)
{
    const float* feat = (const float*)d_in[0];   // [N][64] fp32
    const int*   nbr  = (const int*)  d_in[1];   // [27][N] int32, N == pad idx
    const float* W1   = (const float*)d_in[2];   // [27][64][38]
    const float* W2   = (const float*)d_in[3];   // [27][38][38]

    const size_t hbytes = (size_t)(NPTS + 1) * 64 * 2;   // h incl. zero pad row
    const size_t wbytes = (size_t)K27 * WSTRIDE * 2;     // 221,184

    char* ws  = (char*)d_ws;
    u16* h    = (u16*)ws;
    u16* W1t  = (u16*)(ws + hbytes);
    u16* W2t  = (u16*)(ws + hbytes + wbytes);
    u16* Fb   = (u16*)(ws + hbytes + 2 * wbytes);
    const bool full = ws_size >= hbytes * 2 + 2 * wbytes;   // bf16 feature copy fits?

    prep_w<<<(K27 * 48 * 64 + 255) / 256, 256, 0, stream>>>(
        W1, W2, W1t, W2t,
        h + (size_t)NPTS * 64,
        full ? Fb + (size_t)NPTS * 64 : (u16*)nullptr);

    const int nblk = NPTS / 128;   // 3125, exact
    if (full) {
        prep_feat<<<(int)(((size_t)NPTS * 64 / 8 + 255) / 256), 256, 0, stream>>>(feat, Fb);
        spconv<1, true ><<<nblk, 256, 0, stream>>>(Fb,   nbr, W1t, h);
    } else {
        spconv<1, false><<<nblk, 256, 0, stream>>>(feat, nbr, W1t, h);
    }
    spconv<2, true ><<<nblk, 256, 0, stream>>>(h, nbr, W2t, d_out);
}